// Round 2
// baseline (1847.313 us; speedup 1.0000x reference)
//
#include <hip/hip_runtime.h>
#include <hip/hip_bf16.h>

#define N_NODE 200000
#define EMB 100
#define NNZ 1000000
#define BATCH 1024
#define SLEN 50
#define BE (BATCH * EMB)

#define OFF_HYPER 0LL
#define OFF_LC    20000000LL
#define OFF_NB    20102400LL
#define OFF_LOSS  20204800LL

typedef __hip_bfloat16 bf16;

__device__ __forceinline__ float b2f(bf16 x) { return __bfloat162float(x); }
__device__ __forceinline__ bf16 f2b(float x) { return __float2bfloat16(x); }

// dual-mode load/store: f32 flag selects float32 vs bf16 interpretation
__device__ __forceinline__ float ldf(const void* p, long long i, int f32) {
    return f32 ? ((const float*)p)[i] : b2f(((const bf16*)p)[i]);
}
__device__ __forceinline__ void stf(void* p, long long i, int f32, float v) {
    if (f32) ((float*)p)[i] = v;
    else     ((bf16*)p)[i] = f2b(v);
}

__device__ __forceinline__ float wave_allreduce_sum(float v) {
    for (int m = 32; m > 0; m >>= 1) v += __shfl_xor(v, m, 64);
    return v;
}

// ---- dtype sniff: adj_val ~ U(0,1). If bf16 data, first 64 bf16 values all in [0,1].
// If fp32 data, the interleaved low-mantissa halves are ~random -> fail wildly.
__global__ void sniff_kernel(const void* __restrict__ adjval, int* __restrict__ flag) {
    int f = 0;
    const bf16* p = (const bf16*)adjval;
    for (int i = 0; i < 64; i++) {
        float x = b2f(p[i]);
        if (!(x >= 0.0f && x <= 1.0f)) f = 1;   // NaN also lands here
    }
    *flag = f;
}

// ---- SpMM scatter over column chunk [c0, c0+C): dst[r*C+cc] += val[e] * src[cl*EMB+c0+cc]
// grid = (NNZ, ceil(C/64)), block = 64
__global__ void spmm_scatter(const int* __restrict__ rows, const int* __restrict__ cols,
                             const void* __restrict__ vals, const void* __restrict__ src,
                             float* __restrict__ dst, int C, int c0,
                             const int* __restrict__ flagp) {
    const int f32 = *flagp;
    int e = blockIdx.x;
    int cc = blockIdx.y * 64 + threadIdx.x;
    if (cc >= C) return;
    int r = rows[e], cl = cols[e];
    float v = ldf(vals, e, f32);
    float x = ldf(src, (long long)cl * EMB + c0 + cc, f32);
    atomicAdd(&dst[(long long)r * C + cc], v * x);
}

// buf (N_NODE x C, f32) -> out[n*EMB + c0 + cc]   (h1 staging)
__global__ void buf_to_out(const float* __restrict__ buf, void* __restrict__ out,
                           int C, int c0, const int* __restrict__ flagp) {
    const int f32 = *flagp;
    int n = blockIdx.x;
    int cc = blockIdx.y * 64 + threadIdx.x;
    if (cc >= C) return;
    stf(out, (long long)n * EMB + c0 + cc, f32, buf[(long long)n * C + cc]);
}

// hyper = (emb + h1 + h2)/3; h1 currently resident in out (same slot), h2 in buf
__global__ void final_hyper(const void* __restrict__ emb, void* __restrict__ out,
                            const float* __restrict__ h2buf, int C, int c0,
                            const int* __restrict__ flagp) {
    const int f32 = *flagp;
    int n = blockIdx.x;
    int cc = blockIdx.y * 64 + threadIdx.x;
    if (cc >= C) return;
    long long oi = (long long)n * EMB + c0 + cc;
    float h1 = ldf(out, oi, f32);
    float v = (ldf(emb, oi, f32) + h1 + h2buf[(long long)n * C + cc]) * (1.0f / 3.0f);
    stf(out, oi, f32, v);
}

// rel[b][c] = (1/len[b]) * sum_l emb_pad[items[b][l]][c]
__global__ void rel_kernel(const void* __restrict__ out, const int* __restrict__ items,
                           const void* __restrict__ slen, float* __restrict__ rel,
                           const int* __restrict__ flagp) {
    const int f32 = *flagp;
    int idx = blockIdx.x * blockDim.x + threadIdx.x;
    if (idx >= BE) return;
    int b = idx / EMB, c = idx - b * EMB;
    float s = 0.f;
    for (int l = 0; l < SLEN; l++) {
        int it = items[b * SLEN + l];
        if (it > 0) s += ldf(out, (long long)(it - 1) * EMB + c, f32);
    }
    rel[idx] = s / ldf(slen, b, f32);
}

// Y[i][c] = sum_j M[i][j] * X[j][c]
__global__ void bmm_kernel(const void* __restrict__ M, const float* __restrict__ X,
                           float* __restrict__ Y, const int* __restrict__ flagp) {
    const int f32 = *flagp;
    int idx = blockIdx.x * blockDim.x + threadIdx.x;
    if (idx >= BE) return;
    int i = idx / EMB, c = idx - i * EMB;
    float s = 0.f;
    for (int j = 0; j < BATCH; j++) s += ldf(M, (long long)i * BATCH + j, f32) * X[j * EMB + c];
    Y[idx] = s;
}

// c = selu(rel2); l = c/||c||; sess=l (f32); out_lc=l; ns=sqrt(sum(l^2+1e-6))
__global__ void selu_norm(const float* __restrict__ rel2, float* __restrict__ sess,
                          float* __restrict__ ns, void* __restrict__ out,
                          const int* __restrict__ flagp) {
    const int f32 = *flagp;
    int b = blockIdx.x, t = threadIdx.x;   // 64 threads
    const float sc = 1.0507009873554804934193349852946f;
    const float al = 1.6732632423543772848170429916717f;
    float x0 = (t < EMB) ? rel2[b * EMB + t] : 0.f;
    float x1 = (t + 64 < EMB) ? rel2[b * EMB + t + 64] : 0.f;
    float c0 = (x0 > 0.f) ? sc * x0 : sc * (al * expm1f(x0));
    float c1 = (x1 > 0.f) ? sc * x1 : sc * (al * expm1f(x1));
    if (t >= EMB) c0 = 0.f;
    if (t + 64 >= EMB) c1 = 0.f;
    float nrm = sqrtf(wave_allreduce_sum(c0 * c0 + c1 * c1));
    float l0 = c0 / nrm, l1 = c1 / nrm;
    float nterm = 0.f;
    if (t < EMB) {
        sess[b * EMB + t] = l0;
        stf(out, OFF_LC + b * EMB + t, f32, l0);
        nterm += l0 * l0 + 1e-6f;
    }
    if (t + 64 < EMB) {
        sess[b * EMB + t + 64] = l1;
        stf(out, OFF_LC + b * EMB + t + 64, f32, l1);
        nterm += l1 * l1 + 1e-6f;
    }
    float n2sum = wave_allreduce_sum(nterm);
    if (t == 0) ns[b] = sqrtf(n2sum);
}

// per-row: cos -> softmax -> top3 -> softmax(top3) -> weighted sum of sess rows
__global__ void neighbor_kernel(const float* __restrict__ sess, const float* __restrict__ ns,
                                void* __restrict__ out, const int* __restrict__ flagp) {
    __shared__ float si[EMB];
    __shared__ float p[BATCH];
    __shared__ float wsum[4];
    __shared__ float stv[3];
    __shared__ int sti[3];
    const int f32 = *flagp;
    int i = blockIdx.x, t = threadIdx.x;   // 256 threads
    if (t < EMB) si[t] = sess[i * EMB + t];
    __syncthreads();
    float ni = ns[i];
    float local = 0.f;
    for (int j = t; j < BATCH; j += 256) {
        const float* sj = sess + j * EMB;
        float d = 0.f;
        for (int k = 0; k < EMB; k++) d += si[k] * sj[k];
        float e = expf(d / (ni * ns[j]));
        p[j] = e;
        local += e;
    }
    float w = wave_allreduce_sum(local);
    if ((t & 63) == 0) wsum[t >> 6] = w;
    __syncthreads();
    if (t == 0) {
        float S = wsum[0] + wsum[1] + wsum[2] + wsum[3];
        float v0 = -1e30f, v1 = -1e30f, v2 = -1e30f;
        int i0 = 0, i1 = 0, i2 = 0;
        for (int j = 0; j < BATCH; j++) {
            float pv = p[j];
            if (pv > v0)      { v2 = v1; i2 = i1; v1 = v0; i1 = i0; v0 = pv; i0 = j; }
            else if (pv > v1) { v2 = v1; i2 = i1; v1 = pv; i1 = j; }
            else if (pv > v2) { v2 = pv; i2 = j; }
        }
        float q0 = v0 / S, q1 = v1 / S, q2 = v2 / S;
        float e0 = expf(q0), e1 = expf(q1), e2 = expf(q2);
        float es = e0 + e1 + e2;
        stv[0] = e0 / es; stv[1] = e1 / es; stv[2] = e2 / es;
        sti[0] = i0; sti[1] = i1; sti[2] = i2;
    }
    __syncthreads();
    if (t < EMB) {
        float o = stv[0] * sess[sti[0] * EMB + t]
                + stv[1] * sess[sti[1] * EMB + t]
                + stv[2] * sess[sti[2] * EMB + t];
        stf(out, OFF_NB + i * EMB + t, f32, o);
    }
}

// Y[i][o] = act(sum_k X[i][k]*W[o][k] + b[o]); act: 0=id, 1=ELU
__global__ void linear100(const float* __restrict__ X, const void* __restrict__ Wm,
                          const void* __restrict__ bias, float* __restrict__ Y, int act,
                          const int* __restrict__ flagp) {
    const int f32 = *flagp;
    int idx = blockIdx.x * blockDim.x + threadIdx.x;
    if (idx >= BE) return;
    int i = idx / EMB, o = idx - i * EMB;
    float s = ldf(bias, o, f32);
    const float* x = X + i * EMB;
    for (int k = 0; k < EMB; k++) s += x[k] * ldf(Wm, (long long)o * EMB + k, f32);
    if (act == 1) s = (s > 0.f) ? s : expm1f(s);
    Y[idx] = s;
}

__global__ void cvt_kernel(const void* __restrict__ src, float* __restrict__ dst, int n,
                           const int* __restrict__ flagp) {
    const int f32 = *flagp;
    int i = blockIdx.x * blockDim.x + threadIdx.x;
    if (i < n) dst[i] = ldf(src, i, f32);
}

__global__ void rownorm(const float* __restrict__ Z, float* __restrict__ n) {
    int b = blockIdx.x, t = threadIdx.x;   // 64 threads
    float a = (t < EMB) ? Z[b * EMB + t] : 0.f;
    float c = (t + 64 < EMB) ? Z[b * EMB + t + 64] : 0.f;
    float s = wave_allreduce_sum(a * a + c * c);
    if (t == 0) n[b] = sqrtf(s);
}

__global__ void loss_kernel(const float* __restrict__ z1p, const float* __restrict__ z2p,
                            const float* __restrict__ n1, const float* __restrict__ n2,
                            float* __restrict__ acc) {
    __shared__ float zi[EMB];
    __shared__ float wsum[4];
    __shared__ float sdiag;
    int i = blockIdx.x, t = threadIdx.x;   // 256 threads
    if (t < EMB) zi[t] = z1p[i * EMB + t];
    __syncthreads();
    float ni = n1[i];
    float local = 0.f;
    for (int j = t; j < BATCH; j += 256) {
        const float* zj = z2p + j * EMB;
        float d = 0.f;
        for (int k = 0; k < EMB; k++) d += zi[k] * zj[k];
        float e = expf(d / (ni * n2[j]) / 0.2f);
        local += e;
        if (j == i) sdiag = e;
    }
    float w = wave_allreduce_sum(local);
    if ((t & 63) == 0) wsum[t >> 6] = w;
    __syncthreads();
    if (t == 0) {
        float S = wsum[0] + wsum[1] + wsum[2] + wsum[3];
        float l = -logf(sdiag / (S + 1e-8f));
        atomicAdd(acc, l * (1.0f / BATCH));
    }
}

__global__ void write_loss(const float* __restrict__ acc, void* __restrict__ out,
                           const int* __restrict__ flagp) {
    stf(out, OFF_LOSS, *flagp, acc[0]);
}

extern "C" void kernel_launch(void* const* d_in, const int* in_sizes, int n_in,
                              void* d_out, int out_size, void* d_ws, size_t ws_size,
                              hipStream_t stream) {
    const void* emb  = d_in[0];
    const void* aval = d_in[1];
    const void* Amat = d_in[2];
    const void* Dmat = d_in[3];
    const void* z2   = d_in[4];
    const void* Wcf1 = d_in[5];
    const void* bcf1 = d_in[6];
    const void* Wcf2 = d_in[7];
    const void* bcf2 = d_in[8];
    const void* Wkg1 = d_in[9];
    const void* bkg1 = d_in[10];
    const void* Wkg2 = d_in[11];
    const void* bkg2 = d_in[12];
    const void* slen = d_in[13];
    const int* arow  = (const int*)d_in[14];
    const int* acol  = (const int*)d_in[15];
    const int* items = (const int*)d_in[16];

    // ---- workspace layout (small region first, chunk buffer after) ----
    int* flag = (int*)d_ws;
    float* W  = (float*)((char*)d_ws + 256);
    float* rel  = W;
    float* t1   = rel  + BE;
    float* rel2 = t1   + BE;
    float* sess = rel2 + BE;
    float* tmp  = sess + BE;
    float* z1p  = tmp  + BE;
    float* z2f  = z1p  + BE;
    float* z2p  = z2f  + BE;
    float* ns   = z2p  + BE;         // BATCH
    float* n1   = ns + BATCH;
    float* n2   = n1 + BATCH;
    float* lacc = n2 + BATCH;        // 1
    float* buf  = lacc + 64;         // chunk scatter buffer

    size_t used_bytes = 256 + (size_t)(8 * BE + 3 * BATCH + 64) * sizeof(float);
    size_t avail = (ws_size > used_bytes) ? (ws_size - used_bytes) : 0;
    int C = (int)((avail / sizeof(float)) / N_NODE);
    if (C > EMB) C = EMB;
    if (C < 1) C = 1;

    sniff_kernel<<<1, 1, 0, stream>>>(aval, flag);

    // ---- HyperConv, column-chunked ----
    for (int c0 = 0; c0 < EMB; c0 += C) {
        int Cc = (EMB - c0 < C) ? (EMB - c0) : C;
        dim3 sg(NNZ, (Cc + 63) / 64);
        dim3 ng(N_NODE, (Cc + 63) / 64);
        // layer 1: h1 = Asp @ emb (chunk cols)
        hipMemsetAsync(buf, 0, (size_t)N_NODE * Cc * sizeof(float), stream);
        spmm_scatter<<<sg, 64, 0, stream>>>(arow, acol, aval, emb, buf, Cc, c0, flag);
        buf_to_out<<<ng, 64, 0, stream>>>(buf, d_out, Cc, c0, flag);
        // layer 2: h2 = Asp @ h1 (h1 read from out region)
        hipMemsetAsync(buf, 0, (size_t)N_NODE * Cc * sizeof(float), stream);
        spmm_scatter<<<sg, 64, 0, stream>>>(arow, acol, aval, d_out, buf, Cc, c0, flag);
        // hyper = (emb + h1 + h2)/3, in place
        final_hyper<<<ng, 64, 0, stream>>>(emb, d_out, buf, Cc, c0, flag);
    }

    // ---- RelationGAT ----
    rel_kernel<<<(BE + 255) / 256, 256, 0, stream>>>(d_out, items, slen, rel, flag);
    bmm_kernel<<<(BE + 255) / 256, 256, 0, stream>>>(Amat, rel, t1, flag);   // A @ rel
    bmm_kernel<<<(BE + 255) / 256, 256, 0, stream>>>(Dmat, t1, rel2, flag);  // D @ (A@rel)
    selu_norm<<<BATCH, 64, 0, stream>>>(rel2, sess, ns, d_out, flag);

    // ---- FindNeighbors ----
    neighbor_kernel<<<BATCH, 256, 0, stream>>>(sess, ns, d_out, flag);

    // ---- Contrast_2view ----
    linear100<<<(BE + 255) / 256, 256, 0, stream>>>(sess, Wcf1, bcf1, tmp, 1, flag);
    linear100<<<(BE + 255) / 256, 256, 0, stream>>>(tmp, Wcf2, bcf2, z1p, 0, flag);
    cvt_kernel<<<(BE + 255) / 256, 256, 0, stream>>>(z2, z2f, BE, flag);
    linear100<<<(BE + 255) / 256, 256, 0, stream>>>(z2f, Wkg1, bkg1, tmp, 1, flag);
    linear100<<<(BE + 255) / 256, 256, 0, stream>>>(tmp, Wkg2, bkg2, z2p, 0, flag);
    rownorm<<<BATCH, 64, 0, stream>>>(z1p, n1);
    rownorm<<<BATCH, 64, 0, stream>>>(z2p, n2);
    hipMemsetAsync(lacc, 0, sizeof(float), stream);
    loss_kernel<<<BATCH, 256, 0, stream>>>(z1p, z2p, n1, n2, lacc);
    write_loss<<<1, 1, 0, stream>>>(lacc, d_out, flag);
}

// Round 3
// 1187.227 us; speedup vs baseline: 1.5560x; 1.5560x over previous
//
#include <hip/hip_runtime.h>
#include <hip/hip_bf16.h>

#define N_NODE 200000
#define EMB 100
#define NNZ 1000000
#define BATCH 1024
#define SLEN 50
#define BE (BATCH * EMB)
#define SCAN_BLK 1024

#define OFF_HYPER 0LL
#define OFF_LC    20000000LL
#define OFF_NB    20102400LL
#define OFF_LOSS  20204800LL

typedef __hip_bfloat16 bf16;

__device__ __forceinline__ float b2f(bf16 x) { return __bfloat162float(x); }
__device__ __forceinline__ bf16 f2b(float x) { return __float2bfloat16(x); }

// dual-mode load/store: f32 flag selects float32 vs bf16 interpretation
__device__ __forceinline__ float ldf(const void* p, long long i, int f32) {
    return f32 ? ((const float*)p)[i] : b2f(((const bf16*)p)[i]);
}
__device__ __forceinline__ void stf(void* p, long long i, int f32, float v) {
    if (f32) ((float*)p)[i] = v;
    else     ((bf16*)p)[i] = f2b(v);
}

__device__ __forceinline__ float wave_allreduce_sum(float v) {
    for (int m = 32; m > 0; m >>= 1) v += __shfl_xor(v, m, 64);
    return v;
}

// ---- dtype sniff: adj_val ~ U(0,1). bf16 data -> first 64 bf16 values all in [0,1].
__global__ void sniff_kernel(const void* __restrict__ adjval, int* __restrict__ flag) {
    int f = 0;
    const bf16* p = (const bf16*)adjval;
    for (int i = 0; i < 64; i++) {
        float x = b2f(p[i]);
        if (!(x >= 0.0f && x <= 1.0f)) f = 1;   // NaN also lands here
    }
    *flag = f;
}

// ================= CSR build =================
__global__ void hist_kernel(const int* __restrict__ rows, int* __restrict__ counts) {
    int e = blockIdx.x * 256 + threadIdx.x;
    if (e < NNZ) atomicAdd(&counts[rows[e]], 1);
}

// inclusive scan within 1024-blocks; write block totals
__global__ void scan_block(const int* __restrict__ counts, int* __restrict__ incl,
                           int* __restrict__ bsums) {
    __shared__ int s[SCAN_BLK];
    int i = blockIdx.x * SCAN_BLK + threadIdx.x;
    int v = (i < N_NODE) ? counts[i] : 0;
    s[threadIdx.x] = v;
    __syncthreads();
    for (int off = 1; off < SCAN_BLK; off <<= 1) {
        int add = (threadIdx.x >= (unsigned)off) ? s[threadIdx.x - off] : 0;
        __syncthreads();
        s[threadIdx.x] += add;
        __syncthreads();
    }
    if (i < N_NODE) incl[i] = s[threadIdx.x];
    if (threadIdx.x == SCAN_BLK - 1) bsums[blockIdx.x] = s[threadIdx.x];
}

__global__ void scan_top(int* __restrict__ bsums, int nb) {   // 1 thread: exclusive scan
    int acc = 0;
    for (int b = 0; b < nb; b++) { int t = bsums[b]; bsums[b] = acc; acc += t; }
}

__global__ void scan_add(const int* __restrict__ counts, const int* __restrict__ incl,
                         const int* __restrict__ bsums, int* __restrict__ row_ptr,
                         int* __restrict__ cursor) {
    int i = blockIdx.x * SCAN_BLK + threadIdx.x;
    if (i < N_NODE) {
        int ex = incl[i] - counts[i] + bsums[blockIdx.x];
        row_ptr[i] = ex;
        cursor[i] = ex;
    }
    if (i == 0) row_ptr[N_NODE] = NNZ;
}

// scatter edges into row-sorted (col,val) arrays
__global__ void permute_edges(const int* __restrict__ arow, const int* __restrict__ acol,
                              const void* __restrict__ aval, int* __restrict__ cursor,
                              int* __restrict__ colp, float* __restrict__ valp,
                              const int* __restrict__ flagp) {
    const int f32 = *flagp;
    int e = blockIdx.x * 256 + threadIdx.x;
    if (e >= NNZ) return;
    int r = arow[e];
    int pos = atomicAdd(&cursor[r], 1);
    colp[pos] = acol[e];
    valp[pos] = ldf(aval, e, f32);
}

// ================= SpMM gather =================
// layer 1: h1[r] = sum_k val * emb[col]   (block per row, lane = column)
__global__ void spmm_gather1(const int* __restrict__ row_ptr, const int* __restrict__ colp,
                             const float* __restrict__ valp, const void* __restrict__ emb,
                             bf16* __restrict__ h1, const int* __restrict__ flagp) {
    const int f32 = *flagp;
    int r = blockIdx.x, t = threadIdx.x;   // 128 threads, 100 active
    if (t >= EMB) return;
    int k0 = row_ptr[r], k1 = row_ptr[r + 1];
    float acc = 0.f;
    for (int k = k0; k < k1; k++) {
        int cl = colp[k];
        float v = valp[k];
        acc += v * ldf(emb, (long long)cl * EMB + t, f32);
    }
    h1[(long long)r * EMB + t] = f2b(acc);
}

// layer 2 + final: hyper[r] = (emb[r] + h1[r] + sum_k val*h1[col]) / 3  -> d_out
__global__ void spmm_gather2(const int* __restrict__ row_ptr, const int* __restrict__ colp,
                             const float* __restrict__ valp, const void* __restrict__ emb,
                             const bf16* __restrict__ h1, void* __restrict__ out,
                             const int* __restrict__ flagp) {
    const int f32 = *flagp;
    int r = blockIdx.x, t = threadIdx.x;
    if (t >= EMB) return;
    int k0 = row_ptr[r], k1 = row_ptr[r + 1];
    float acc = 0.f;
    for (int k = k0; k < k1; k++) {
        int cl = colp[k];
        float v = valp[k];
        acc += v * b2f(h1[(long long)cl * EMB + t]);
    }
    long long oi = (long long)r * EMB + t;
    float hy = (ldf(emb, oi, f32) + b2f(h1[oi]) + acc) * (1.0f / 3.0f);
    stf(out, oi, f32, hy);
}

// ================= downstream =================
// rel[b] = (1/len[b]) * sum_l emb_pad[items[b][l]]   (block per b, lane = column)
__global__ void rel_rows(const void* __restrict__ out, const int* __restrict__ items,
                         const void* __restrict__ slen, float* __restrict__ rel,
                         const int* __restrict__ flagp) {
    const int f32 = *flagp;
    int b = blockIdx.x, t = threadIdx.x;   // 128 threads, 100 active
    if (t >= EMB) return;
    float s = 0.f;
    for (int l = 0; l < SLEN; l++) {
        int it = items[b * SLEN + l];      // wave-uniform
        if (it > 0) s += ldf(out, (long long)(it - 1) * EMB + t, f32);
    }
    rel[b * EMB + t] = s / ldf(slen, b, f32);
}

// Y[i] = M[i,:] @ X   (block per i, lane = column; M load is broadcast)
__global__ void bmm_rows(const void* __restrict__ M, const float* __restrict__ X,
                         float* __restrict__ Y, const int* __restrict__ flagp) {
    const int f32 = *flagp;
    int i = blockIdx.x, t = threadIdx.x;   // 128 threads, 100 active
    if (t >= EMB) return;
    float s = 0.f;
    for (int j = 0; j < BATCH; j++)
        s += ldf(M, (long long)i * BATCH + j, f32) * X[j * EMB + t];
    Y[i * EMB + t] = s;
}

// c = selu(rel2); l = c/||c||; sess=l (f32); out_lc=l; ns=sqrt(sum(l^2+1e-6))
__global__ void selu_norm(const float* __restrict__ rel2, float* __restrict__ sess,
                          float* __restrict__ ns, void* __restrict__ out,
                          const int* __restrict__ flagp) {
    const int f32 = *flagp;
    int b = blockIdx.x, t = threadIdx.x;   // 64 threads
    const float sc = 1.0507009873554804934193349852946f;
    const float al = 1.6732632423543772848170429916717f;
    float x0 = (t < EMB) ? rel2[b * EMB + t] : 0.f;
    float x1 = (t + 64 < EMB) ? rel2[b * EMB + t + 64] : 0.f;
    float c0 = (x0 > 0.f) ? sc * x0 : sc * (al * expm1f(x0));
    float c1 = (x1 > 0.f) ? sc * x1 : sc * (al * expm1f(x1));
    if (t >= EMB) c0 = 0.f;
    if (t + 64 >= EMB) c1 = 0.f;
    float nrm = sqrtf(wave_allreduce_sum(c0 * c0 + c1 * c1));
    float l0 = c0 / nrm, l1 = c1 / nrm;
    float nterm = 0.f;
    if (t < EMB) {
        sess[b * EMB + t] = l0;
        stf(out, OFF_LC + b * EMB + t, f32, l0);
        nterm += l0 * l0 + 1e-6f;
    }
    if (t + 64 < EMB) {
        sess[b * EMB + t + 64] = l1;
        stf(out, OFF_LC + b * EMB + t + 64, f32, l1);
        nterm += l1 * l1 + 1e-6f;
    }
    float n2sum = wave_allreduce_sum(nterm);
    if (t == 0) ns[b] = sqrtf(n2sum);
}

// per-row: cos -> softmax -> top3 -> softmax(top3) -> weighted sum of sess rows
__global__ void neighbor_kernel(const float* __restrict__ sess, const float* __restrict__ ns,
                                void* __restrict__ out, const int* __restrict__ flagp) {
    __shared__ float si[EMB];
    __shared__ float p[BATCH];
    __shared__ float wsum[4];
    __shared__ float stv[3];
    __shared__ int sti[3];
    const int f32 = *flagp;
    int i = blockIdx.x, t = threadIdx.x;   // 256 threads
    if (t < EMB) si[t] = sess[i * EMB + t];
    __syncthreads();
    float ni = ns[i];
    float local = 0.f;
    for (int j = t; j < BATCH; j += 256) {
        const float* sj = sess + j * EMB;
        float d = 0.f;
        for (int k = 0; k < EMB; k++) d += si[k] * sj[k];
        float e = expf(d / (ni * ns[j]));
        p[j] = e;
        local += e;
    }
    float w = wave_allreduce_sum(local);
    if ((t & 63) == 0) wsum[t >> 6] = w;
    __syncthreads();
    if (t == 0) {
        float S = wsum[0] + wsum[1] + wsum[2] + wsum[3];
        float v0 = -1e30f, v1 = -1e30f, v2 = -1e30f;
        int i0 = 0, i1 = 0, i2 = 0;
        for (int j = 0; j < BATCH; j++) {
            float pv = p[j];
            if (pv > v0)      { v2 = v1; i2 = i1; v1 = v0; i1 = i0; v0 = pv; i0 = j; }
            else if (pv > v1) { v2 = v1; i2 = i1; v1 = pv; i1 = j; }
            else if (pv > v2) { v2 = pv; i2 = j; }
        }
        float q0 = v0 / S, q1 = v1 / S, q2 = v2 / S;
        float e0 = expf(q0), e1 = expf(q1), e2 = expf(q2);
        float es = e0 + e1 + e2;
        stv[0] = e0 / es; stv[1] = e1 / es; stv[2] = e2 / es;
        sti[0] = i0; sti[1] = i1; sti[2] = i2;
    }
    __syncthreads();
    if (t < EMB) {
        float o = stv[0] * sess[sti[0] * EMB + t]
                + stv[1] * sess[sti[1] * EMB + t]
                + stv[2] * sess[sti[2] * EMB + t];
        stf(out, OFF_NB + i * EMB + t, f32, o);
    }
}

// Y[i][o] = act(sum_k X[i][k]*W[o][k] + b[o]); act: 0=id, 1=ELU
__global__ void linear100(const float* __restrict__ X, const void* __restrict__ Wm,
                          const void* __restrict__ bias, float* __restrict__ Y, int act,
                          const int* __restrict__ flagp) {
    const int f32 = *flagp;
    int idx = blockIdx.x * blockDim.x + threadIdx.x;
    if (idx >= BE) return;
    int i = idx / EMB, o = idx - i * EMB;
    float s = ldf(bias, o, f32);
    const float* x = X + i * EMB;
    for (int k = 0; k < EMB; k++) s += x[k] * ldf(Wm, (long long)o * EMB + k, f32);
    if (act == 1) s = (s > 0.f) ? s : expm1f(s);
    Y[idx] = s;
}

__global__ void cvt_kernel(const void* __restrict__ src, float* __restrict__ dst, int n,
                           const int* __restrict__ flagp) {
    const int f32 = *flagp;
    int i = blockIdx.x * blockDim.x + threadIdx.x;
    if (i < n) dst[i] = ldf(src, i, f32);
}

__global__ void rownorm(const float* __restrict__ Z, float* __restrict__ n) {
    int b = blockIdx.x, t = threadIdx.x;   // 64 threads
    float a = (t < EMB) ? Z[b * EMB + t] : 0.f;
    float c = (t + 64 < EMB) ? Z[b * EMB + t + 64] : 0.f;
    float s = wave_allreduce_sum(a * a + c * c);
    if (t == 0) n[b] = sqrtf(s);
}

__global__ void loss_kernel(const float* __restrict__ z1p, const float* __restrict__ z2p,
                            const float* __restrict__ n1, const float* __restrict__ n2,
                            float* __restrict__ acc) {
    __shared__ float zi[EMB];
    __shared__ float wsum[4];
    __shared__ float sdiag;
    int i = blockIdx.x, t = threadIdx.x;   // 256 threads
    if (t < EMB) zi[t] = z1p[i * EMB + t];
    __syncthreads();
    float ni = n1[i];
    float local = 0.f;
    for (int j = t; j < BATCH; j += 256) {
        const float* zj = z2p + j * EMB;
        float d = 0.f;
        for (int k = 0; k < EMB; k++) d += zi[k] * zj[k];
        float e = expf(d / (ni * n2[j]) / 0.2f);
        local += e;
        if (j == i) sdiag = e;
    }
    float w = wave_allreduce_sum(local);
    if ((t & 63) == 0) wsum[t >> 6] = w;
    __syncthreads();
    if (t == 0) {
        float S = wsum[0] + wsum[1] + wsum[2] + wsum[3];
        float l = -logf(sdiag / (S + 1e-8f));
        atomicAdd(acc, l * (1.0f / BATCH));
    }
}

__global__ void write_loss(const float* __restrict__ acc, void* __restrict__ out,
                           const int* __restrict__ flagp) {
    stf(out, OFF_LOSS, *flagp, acc[0]);
}

extern "C" void kernel_launch(void* const* d_in, const int* in_sizes, int n_in,
                              void* d_out, int out_size, void* d_ws, size_t ws_size,
                              hipStream_t stream) {
    const void* emb  = d_in[0];
    const void* aval = d_in[1];
    const void* Amat = d_in[2];
    const void* Dmat = d_in[3];
    const void* z2   = d_in[4];
    const void* Wcf1 = d_in[5];
    const void* bcf1 = d_in[6];
    const void* Wcf2 = d_in[7];
    const void* bcf2 = d_in[8];
    const void* Wkg1 = d_in[9];
    const void* bkg1 = d_in[10];
    const void* Wkg2 = d_in[11];
    const void* bkg2 = d_in[12];
    const void* slen = d_in[13];
    const int* arow  = (const int*)d_in[14];
    const int* acol  = (const int*)d_in[15];
    const int* items = (const int*)d_in[16];

    // ---- workspace layout ----
    int* flag      = (int*)d_ws;
    int* counts    = (int*)((char*)d_ws + 256);        // N_NODE
    int* row_ptr   = counts + N_NODE;                  // N_NODE+1
    int* cursor    = row_ptr + N_NODE + 64;            // N_NODE
    int* bsums     = cursor + N_NODE;                  // 256
    int* colp      = bsums + 256;                      // NNZ (also incl-scan scratch)
    float* valp    = (float*)(colp + NNZ);             // NNZ
    bf16* h1buf    = (bf16*)(valp + NNZ);              // N_NODE*EMB bf16 (40 MB)
    float* fsmall  = (float*)(h1buf + (long long)N_NODE * EMB);
    float* rel  = fsmall;
    float* t1   = rel  + BE;
    float* rel2 = t1   + BE;
    float* sess = rel2 + BE;
    float* tmp  = sess + BE;
    float* z1p  = tmp  + BE;
    float* z2f  = z1p  + BE;
    float* z2p  = z2f  + BE;
    float* ns   = z2p  + BE;
    float* n1   = ns + BATCH;
    float* n2   = n1 + BATCH;
    float* lacc = n2 + BATCH;

    const int nscan = (N_NODE + SCAN_BLK - 1) / SCAN_BLK;   // 196

    sniff_kernel<<<1, 1, 0, stream>>>(aval, flag);

    // ---- CSR build ----
    hipMemsetAsync(counts, 0, (size_t)N_NODE * sizeof(int), stream);
    hist_kernel<<<(NNZ + 255) / 256, 256, 0, stream>>>(arow, counts);
    scan_block<<<nscan, SCAN_BLK, 0, stream>>>(counts, colp /*incl scratch*/, bsums);
    scan_top<<<1, 1, 0, stream>>>(bsums, nscan);
    scan_add<<<nscan, SCAN_BLK, 0, stream>>>(counts, colp, bsums, row_ptr, cursor);
    permute_edges<<<(NNZ + 255) / 256, 256, 0, stream>>>(arow, acol, aval, cursor,
                                                         colp, valp, flag);

    // ---- HyperConv via gather (no atomics) ----
    spmm_gather1<<<N_NODE, 128, 0, stream>>>(row_ptr, colp, valp, emb, h1buf, flag);
    spmm_gather2<<<N_NODE, 128, 0, stream>>>(row_ptr, colp, valp, emb, h1buf, d_out, flag);

    // ---- RelationGAT ----
    rel_rows<<<BATCH, 128, 0, stream>>>(d_out, items, slen, rel, flag);
    bmm_rows<<<BATCH, 128, 0, stream>>>(Amat, rel, t1, flag);   // A @ rel
    bmm_rows<<<BATCH, 128, 0, stream>>>(Dmat, t1, rel2, flag);  // D @ (A@rel)
    selu_norm<<<BATCH, 64, 0, stream>>>(rel2, sess, ns, d_out, flag);

    // ---- FindNeighbors ----
    neighbor_kernel<<<BATCH, 256, 0, stream>>>(sess, ns, d_out, flag);

    // ---- Contrast_2view ----
    linear100<<<(BE + 255) / 256, 256, 0, stream>>>(sess, Wcf1, bcf1, tmp, 1, flag);
    linear100<<<(BE + 255) / 256, 256, 0, stream>>>(tmp, Wcf2, bcf2, z1p, 0, flag);
    cvt_kernel<<<(BE + 255) / 256, 256, 0, stream>>>(z2, z2f, BE, flag);
    linear100<<<(BE + 255) / 256, 256, 0, stream>>>(z2f, Wkg1, bkg1, tmp, 1, flag);
    linear100<<<(BE + 255) / 256, 256, 0, stream>>>(tmp, Wkg2, bkg2, z2p, 0, flag);
    rownorm<<<BATCH, 64, 0, stream>>>(z1p, n1);
    rownorm<<<BATCH, 64, 0, stream>>>(z2p, n2);
    hipMemsetAsync(lacc, 0, sizeof(float), stream);
    loss_kernel<<<BATCH, 256, 0, stream>>>(z1p, z2p, n1, n2, lacc);
    write_loss<<<1, 1, 0, stream>>>(lacc, d_out, flag);
}

// Round 4
// 991.108 us; speedup vs baseline: 1.8639x; 1.1979x over previous
//
#include <hip/hip_runtime.h>
#include <hip/hip_bf16.h>

#define N_NODE 200000
#define EMB 100
#define NNZ 1000000
#define BATCH 1024
#define SLEN 50
#define BE (BATCH * EMB)
#define SCAN_BLK 1024

#define OFF_HYPER 0LL
#define OFF_LC    20000000LL
#define OFF_NB    20102400LL
#define OFF_LOSS  20204800LL

typedef __hip_bfloat16 bf16;

__device__ __forceinline__ float b2f(bf16 x) { return __bfloat162float(x); }
__device__ __forceinline__ bf16 f2b(float x) { return __float2bfloat16(x); }

__device__ __forceinline__ float ldf(const void* p, long long i, int f32) {
    return f32 ? ((const float*)p)[i] : b2f(((const bf16*)p)[i]);
}
__device__ __forceinline__ void stf(void* p, long long i, int f32, float v) {
    if (f32) ((float*)p)[i] = v;
    else     ((bf16*)p)[i] = f2b(v);
}

__device__ __forceinline__ float wave_allreduce_sum(float v) {
    for (int m = 32; m > 0; m >>= 1) v += __shfl_xor(v, m, 64);
    return v;
}

__global__ void sniff_kernel(const void* __restrict__ adjval, int* __restrict__ flag) {
    int f = 0;
    const bf16* p = (const bf16*)adjval;
    for (int i = 0; i < 64; i++) {
        float x = b2f(p[i]);
        if (!(x >= 0.0f && x <= 1.0f)) f = 1;
    }
    *flag = f;
}

// ================= CSR build =================
__global__ void hist_kernel(const int* __restrict__ rows, int* __restrict__ counts) {
    int e = blockIdx.x * 256 + threadIdx.x;
    if (e < NNZ) atomicAdd(&counts[rows[e]], 1);
}

__global__ void scan_block(const int* __restrict__ counts, int* __restrict__ incl,
                           int* __restrict__ bsums) {
    __shared__ int s[SCAN_BLK];
    int i = blockIdx.x * SCAN_BLK + threadIdx.x;
    int v = (i < N_NODE) ? counts[i] : 0;
    s[threadIdx.x] = v;
    __syncthreads();
    for (int off = 1; off < SCAN_BLK; off <<= 1) {
        int add = (threadIdx.x >= (unsigned)off) ? s[threadIdx.x - off] : 0;
        __syncthreads();
        s[threadIdx.x] += add;
        __syncthreads();
    }
    if (i < N_NODE) incl[i] = s[threadIdx.x];
    if (threadIdx.x == SCAN_BLK - 1) bsums[blockIdx.x] = s[threadIdx.x];
}

__global__ void scan_top(int* __restrict__ bsums, int nb) {
    int acc = 0;
    for (int b = 0; b < nb; b++) { int t = bsums[b]; bsums[b] = acc; acc += t; }
}

// NOTE: cursor may alias counts (read-then-write within same thread index)
__global__ void scan_add(const int* __restrict__ counts, const int* __restrict__ incl,
                         const int* __restrict__ bsums, int* __restrict__ row_ptr,
                         int* __restrict__ cursor) {
    int i = blockIdx.x * SCAN_BLK + threadIdx.x;
    if (i < N_NODE) {
        int ex = incl[i] - counts[i] + bsums[blockIdx.x];
        row_ptr[i] = ex;
        cursor[i] = ex;
    }
    if (i == 0) row_ptr[N_NODE] = NNZ;
}

__global__ void permute_edges(const int* __restrict__ arow, const int* __restrict__ acol,
                              const void* __restrict__ aval, int* __restrict__ cursor,
                              int* __restrict__ colp, float* __restrict__ valp,
                              const int* __restrict__ flagp) {
    const int f32 = *flagp;
    int e = blockIdx.x * 256 + threadIdx.x;
    if (e >= NNZ) return;
    int r = arow[e];
    int pos = atomicAdd(&cursor[r], 1);
    colp[pos] = acol[e];
    valp[pos] = ldf(aval, e, f32);
}

// ================= SpMM gather =================
__global__ void spmm_gather1(const int* __restrict__ row_ptr, const int* __restrict__ colp,
                             const float* __restrict__ valp, const void* __restrict__ emb,
                             bf16* __restrict__ h1, const int* __restrict__ flagp) {
    const int f32 = *flagp;
    int r = blockIdx.x, t = threadIdx.x;   // 128 threads, 100 active
    if (t >= EMB) return;
    int k0 = row_ptr[r], k1 = row_ptr[r + 1];
    float acc = 0.f;
    for (int k = k0; k < k1; k++) {
        int cl = colp[k];
        float v = valp[k];
        acc += v * ldf(emb, (long long)cl * EMB + t, f32);
    }
    h1[(long long)r * EMB + t] = f2b(acc);
}

__global__ void spmm_gather2(const int* __restrict__ row_ptr, const int* __restrict__ colp,
                             const float* __restrict__ valp, const void* __restrict__ emb,
                             const bf16* __restrict__ h1, void* __restrict__ out,
                             const int* __restrict__ flagp) {
    const int f32 = *flagp;
    int r = blockIdx.x, t = threadIdx.x;
    if (t >= EMB) return;
    int k0 = row_ptr[r], k1 = row_ptr[r + 1];
    float acc = 0.f;
    for (int k = k0; k < k1; k++) {
        int cl = colp[k];
        float v = valp[k];
        acc += v * b2f(h1[(long long)cl * EMB + t]);
    }
    long long oi = (long long)r * EMB + t;
    float hy = (ldf(emb, oi, f32) + b2f(h1[oi]) + acc) * (1.0f / 3.0f);
    stf(out, oi, f32, hy);
}

// ================= downstream =================
__global__ void rel_rows(const void* __restrict__ out, const int* __restrict__ items,
                         const void* __restrict__ slen, float* __restrict__ rel,
                         const int* __restrict__ flagp) {
    const int f32 = *flagp;
    int b = blockIdx.x, t = threadIdx.x;   // 128 threads, 100 active
    if (t >= EMB) return;
    float s = 0.f;
    for (int l = 0; l < SLEN; l++) {
        int it = items[b * SLEN + l];
        if (it > 0) s += ldf(out, (long long)(it - 1) * EMB + t, f32);
    }
    rel[b * EMB + t] = s / ldf(slen, b, f32);
}

__global__ void bmm_rows(const void* __restrict__ M, const float* __restrict__ X,
                         float* __restrict__ Y, const int* __restrict__ flagp) {
    const int f32 = *flagp;
    int i = blockIdx.x, t = threadIdx.x;   // 128 threads, 100 active
    if (t >= EMB) return;
    float s = 0.f;
    for (int j = 0; j < BATCH; j++)
        s += ldf(M, (long long)i * BATCH + j, f32) * X[j * EMB + t];
    Y[i * EMB + t] = s;
}

// c = selu(rel2); l=c/||c||; sess (row-major), sessT (col-major), out_lc, ns
__global__ void selu_norm(const float* __restrict__ rel2, float* __restrict__ sess,
                          float* __restrict__ sessT, float* __restrict__ ns,
                          void* __restrict__ out, const int* __restrict__ flagp) {
    const int f32 = *flagp;
    int b = blockIdx.x, t = threadIdx.x;   // 64 threads
    const float sc = 1.0507009873554804934193349852946f;
    const float al = 1.6732632423543772848170429916717f;
    float x0 = (t < EMB) ? rel2[b * EMB + t] : 0.f;
    float x1 = (t + 64 < EMB) ? rel2[b * EMB + t + 64] : 0.f;
    float c0 = (x0 > 0.f) ? sc * x0 : sc * (al * expm1f(x0));
    float c1 = (x1 > 0.f) ? sc * x1 : sc * (al * expm1f(x1));
    if (t >= EMB) c0 = 0.f;
    if (t + 64 >= EMB) c1 = 0.f;
    float nrm = sqrtf(wave_allreduce_sum(c0 * c0 + c1 * c1));
    float l0 = c0 / nrm, l1 = c1 / nrm;
    float nterm = 0.f;
    if (t < EMB) {
        sess[b * EMB + t] = l0;
        sessT[t * BATCH + b] = l0;
        stf(out, OFF_LC + b * EMB + t, f32, l0);
        nterm += l0 * l0 + 1e-6f;
    }
    if (t + 64 < EMB) {
        sess[b * EMB + t + 64] = l1;
        sessT[(t + 64) * BATCH + b] = l1;
        stf(out, OFF_LC + b * EMB + t + 64, f32, l1);
        nterm += l1 * l1 + 1e-6f;
    }
    float n2sum = wave_allreduce_sum(nterm);
    if (t == 0) ns[b] = sqrtf(n2sum);
}

// block-wide argmax helper state: 3 rounds of (max, min-index) reduction
__global__ void neighbor_kernel(const float* __restrict__ sess, const float* __restrict__ sessT,
                                const float* __restrict__ ns, void* __restrict__ out,
                                const int* __restrict__ flagp) {
    __shared__ float si[EMB];
    __shared__ float red[4];
    __shared__ float wrv[4]; __shared__ int wri[4];
    __shared__ float chv[3]; __shared__ int chi[3];
    __shared__ float stv[3];
    const int f32 = *flagp;
    int i = blockIdx.x, t = threadIdx.x;   // 256 threads
    if (t < EMB) si[t] = sess[i * EMB + t];
    __syncthreads();
    float ni = ns[i];
    float d0 = 0.f, d1 = 0.f, d2 = 0.f, d3 = 0.f;
    for (int k = 0; k < EMB; k++) {
        float sv = si[k];
        const float* row = sessT + k * BATCH;
        d0 += sv * row[t];
        d1 += sv * row[t + 256];
        d2 += sv * row[t + 512];
        d3 += sv * row[t + 768];
    }
    float pv0 = expf(d0 / (ni * ns[t]));
    float pv1 = expf(d1 / (ni * ns[t + 256]));
    float pv2 = expf(d2 / (ni * ns[t + 512]));
    float pv3 = expf(d3 / (ni * ns[t + 768]));
    float local = pv0 + pv1 + pv2 + pv3;
    float w = wave_allreduce_sum(local);
    if ((t & 63) == 0) red[t >> 6] = w;
    __syncthreads();
    float S = red[0] + red[1] + red[2] + red[3];

    // 3 rounds of block argmax with exclusion (tie -> smaller index)
    int c0 = -1, c1 = -1, c2 = -1;
    float pv[4] = {pv0, pv1, pv2, pv3};
    for (int r = 0; r < 3; r++) {
        float bv = -1e30f; int bi = 0x7fffffff;
        #pragma unroll
        for (int m = 0; m < 4; m++) {
            int j = t + (m << 8);
            if (j == c0 || j == c1 || j == c2) continue;
            float v = pv[m];
            if (v > bv || (v == bv && j < bi)) { bv = v; bi = j; }
        }
        #pragma unroll
        for (int off = 1; off < 64; off <<= 1) {
            float ov = __shfl_xor(bv, off);
            int oi = __shfl_xor(bi, off);
            if (ov > bv || (ov == bv && oi < bi)) { bv = ov; bi = oi; }
        }
        if ((t & 63) == 0) { wrv[t >> 6] = bv; wri[t >> 6] = bi; }
        __syncthreads();
        if (t == 0) {
            float fv = wrv[0]; int fi = wri[0];
            for (int wq = 1; wq < 4; wq++) {
                if (wrv[wq] > fv || (wrv[wq] == fv && wri[wq] < fi)) { fv = wrv[wq]; fi = wri[wq]; }
            }
            chv[r] = fv; chi[r] = fi;
        }
        __syncthreads();
        if (r == 0) c0 = chi[0];
        else if (r == 1) c1 = chi[1];
        else c2 = chi[2];
    }
    if (t == 0) {
        float e0 = expf(chv[0] / S), e1 = expf(chv[1] / S), e2 = expf(chv[2] / S);
        float es = e0 + e1 + e2;
        stv[0] = e0 / es; stv[1] = e1 / es; stv[2] = e2 / es;
    }
    __syncthreads();
    if (t < EMB) {
        float o = stv[0] * sess[chi[0] * EMB + t]
                + stv[1] * sess[chi[1] * EMB + t]
                + stv[2] * sess[chi[2] * EMB + t];
        stf(out, OFF_NB + i * EMB + t, f32, o);
    }
}

// Y[i][o] = act(X[i,:] @ W[o,:] + b[o]); W staged transposed in LDS
__global__ void linear100(const float* __restrict__ X, const void* __restrict__ Wm,
                          const void* __restrict__ bias, float* __restrict__ Y,
                          float* __restrict__ YT, int act, const int* __restrict__ flagp) {
    __shared__ float wT[EMB * EMB];   // 40 KB
    __shared__ float bsh[EMB];
    const int f32 = *flagp;
    int t = threadIdx.x;
    for (int idx = t; idx < EMB * EMB; idx += 256) {
        int o = idx / EMB, k = idx - o * EMB;
        wT[k * EMB + o] = ldf(Wm, idx, f32);
    }
    if (t < EMB) bsh[t] = ldf(bias, t, f32);
    __syncthreads();
    int idx = blockIdx.x * 256 + t;
    if (idx >= BE) return;
    int i = idx / EMB, o = idx - i * EMB;
    float s = bsh[o];
    const float* x = X + i * EMB;
    for (int k = 0; k < EMB; k++) s += x[k] * wT[k * EMB + o];
    if (act == 1) s = (s > 0.f) ? s : expm1f(s);
    Y[idx] = s;
    if (YT) YT[o * BATCH + i] = s;
}

__global__ void cvt_kernel(const void* __restrict__ src, float* __restrict__ dst, int n,
                           const int* __restrict__ flagp) {
    const int f32 = *flagp;
    int i = blockIdx.x * blockDim.x + threadIdx.x;
    if (i < n) dst[i] = ldf(src, i, f32);
}

__global__ void rownorm(const float* __restrict__ Z, float* __restrict__ n) {
    int b = blockIdx.x, t = threadIdx.x;   // 64 threads
    float a = (t < EMB) ? Z[b * EMB + t] : 0.f;
    float c = (t + 64 < EMB) ? Z[b * EMB + t + 64] : 0.f;
    float s = wave_allreduce_sum(a * a + c * c);
    if (t == 0) n[b] = sqrtf(s);
}

__global__ void loss_kernel(const float* __restrict__ z1p, const float* __restrict__ z2pT,
                            const float* __restrict__ n1, const float* __restrict__ n2,
                            float* __restrict__ acc) {
    __shared__ float zi[EMB];
    __shared__ float red[4];
    __shared__ float sdiag;
    int i = blockIdx.x, t = threadIdx.x;   // 256 threads
    if (t < EMB) zi[t] = z1p[i * EMB + t];
    __syncthreads();
    float ni = n1[i];
    float d0 = 0.f, d1 = 0.f, d2 = 0.f, d3 = 0.f;
    for (int k = 0; k < EMB; k++) {
        float zv = zi[k];
        const float* row = z2pT + k * BATCH;
        d0 += zv * row[t];
        d1 += zv * row[t + 256];
        d2 += zv * row[t + 512];
        d3 += zv * row[t + 768];
    }
    float e0 = expf(d0 / (ni * n2[t]) * 5.0f);
    float e1 = expf(d1 / (ni * n2[t + 256]) * 5.0f);
    float e2 = expf(d2 / (ni * n2[t + 512]) * 5.0f);
    float e3 = expf(d3 / (ni * n2[t + 768]) * 5.0f);
    if (t == (i & 255)) {
        int m = i >> 8;
        sdiag = (m == 0) ? e0 : (m == 1) ? e1 : (m == 2) ? e2 : e3;
    }
    float local = e0 + e1 + e2 + e3;
    float w = wave_allreduce_sum(local);
    if ((t & 63) == 0) red[t >> 6] = w;
    __syncthreads();
    if (t == 0) {
        float S = red[0] + red[1] + red[2] + red[3];
        float l = -logf(sdiag / (S + 1e-8f));
        atomicAdd(acc, l * (1.0f / BATCH));
    }
}

__global__ void write_loss(const float* __restrict__ acc, void* __restrict__ out,
                           const int* __restrict__ flagp) {
    stf(out, OFF_LOSS, *flagp, acc[0]);
}

extern "C" void kernel_launch(void* const* d_in, const int* in_sizes, int n_in,
                              void* d_out, int out_size, void* d_ws, size_t ws_size,
                              hipStream_t stream) {
    const void* emb  = d_in[0];
    const void* aval = d_in[1];
    const void* Amat = d_in[2];
    const void* Dmat = d_in[3];
    const void* z2   = d_in[4];
    const void* Wcf1 = d_in[5];
    const void* bcf1 = d_in[6];
    const void* Wcf2 = d_in[7];
    const void* bcf2 = d_in[8];
    const void* Wkg1 = d_in[9];
    const void* bkg1 = d_in[10];
    const void* Wkg2 = d_in[11];
    const void* bkg2 = d_in[12];
    const void* slen = d_in[13];
    const int* arow  = (const int*)d_in[14];
    const int* acol  = (const int*)d_in[15];
    const int* items = (const int*)d_in[16];

    // ---- workspace layout ----
    int* flag      = (int*)d_ws;
    int* counts    = (int*)((char*)d_ws + 256);        // N_NODE (aliased as cursor)
    int* cursor    = counts;                           // alias: dead after scan_add reads
    int* row_ptr   = counts + N_NODE;                  // N_NODE+1
    int* bsums     = row_ptr + N_NODE + 64;            // 256
    int* colp      = bsums + 256;                      // NNZ (also incl-scan scratch)
    float* valp    = (float*)(colp + NNZ);             // NNZ
    bf16* h1buf    = (bf16*)(valp + NNZ);              // N_NODE*EMB bf16 (40 MB)
    float* fsmall  = (float*)(h1buf + (long long)N_NODE * EMB);
    float* rel   = fsmall;
    float* t1    = rel  + BE;
    float* rel2  = t1   + BE;
    float* sess  = rel2 + BE;
    float* sessT = sess + BE;
    float* tmp   = sessT + BE;
    float* z1p   = tmp  + BE;
    float* z2f   = z1p  + BE;
    float* z2p   = z2f  + BE;
    float* z2pT  = z2p  + BE;
    float* ns    = z2pT + BE;
    float* n1    = ns + BATCH;
    float* n2    = n1 + BATCH;
    float* lacc  = n2 + BATCH;

    const int nscan = (N_NODE + SCAN_BLK - 1) / SCAN_BLK;

    sniff_kernel<<<1, 1, 0, stream>>>(aval, flag);

    // ---- CSR build ----
    hipMemsetAsync(counts, 0, (size_t)N_NODE * sizeof(int), stream);
    hist_kernel<<<(NNZ + 255) / 256, 256, 0, stream>>>(arow, counts);
    scan_block<<<nscan, SCAN_BLK, 0, stream>>>(counts, colp, bsums);
    scan_top<<<1, 1, 0, stream>>>(bsums, nscan);
    scan_add<<<nscan, SCAN_BLK, 0, stream>>>(counts, colp, bsums, row_ptr, cursor);
    permute_edges<<<(NNZ + 255) / 256, 256, 0, stream>>>(arow, acol, aval, cursor,
                                                         colp, valp, flag);

    // ---- HyperConv via gather ----
    spmm_gather1<<<N_NODE, 128, 0, stream>>>(row_ptr, colp, valp, emb, h1buf, flag);
    spmm_gather2<<<N_NODE, 128, 0, stream>>>(row_ptr, colp, valp, emb, h1buf, d_out, flag);

    // ---- RelationGAT ----
    rel_rows<<<BATCH, 128, 0, stream>>>(d_out, items, slen, rel, flag);
    bmm_rows<<<BATCH, 128, 0, stream>>>(Amat, rel, t1, flag);
    bmm_rows<<<BATCH, 128, 0, stream>>>(Dmat, t1, rel2, flag);
    selu_norm<<<BATCH, 64, 0, stream>>>(rel2, sess, sessT, ns, d_out, flag);

    // ---- FindNeighbors ----
    neighbor_kernel<<<BATCH, 256, 0, stream>>>(sess, sessT, ns, d_out, flag);

    // ---- Contrast_2view ----
    linear100<<<(BE + 255) / 256, 256, 0, stream>>>(sess, Wcf1, bcf1, tmp, nullptr, 1, flag);
    linear100<<<(BE + 255) / 256, 256, 0, stream>>>(tmp, Wcf2, bcf2, z1p, nullptr, 0, flag);
    cvt_kernel<<<(BE + 255) / 256, 256, 0, stream>>>(z2, z2f, BE, flag);
    linear100<<<(BE + 255) / 256, 256, 0, stream>>>(z2f, Wkg1, bkg1, tmp, nullptr, 1, flag);
    linear100<<<(BE + 255) / 256, 256, 0, stream>>>(tmp, Wkg2, bkg2, z2p, z2pT, 0, flag);
    rownorm<<<BATCH, 64, 0, stream>>>(z1p, n1);
    rownorm<<<BATCH, 64, 0, stream>>>(z2p, n2);
    hipMemsetAsync(lacc, 0, sizeof(float), stream);
    loss_kernel<<<BATCH, 256, 0, stream>>>(z1p, z2pT, n1, n2, lacc);
    write_loss<<<1, 1, 0, stream>>>(lacc, d_out, flag);
}

// Round 5
// 793.026 us; speedup vs baseline: 2.3294x; 1.2498x over previous
//
#include <hip/hip_runtime.h>
#include <hip/hip_bf16.h>

#define N_NODE 200000
#define EMB 100
#define NNZ 1000000
#define BATCH 1024
#define SLEN 50
#define BE (BATCH * EMB)
#define SCAN_BLK 1024
#define PROJ_ROWS 8

#define OFF_LC    20000000LL
#define OFF_NB    20102400LL
#define OFF_LOSS  20204800LL

typedef __hip_bfloat16 bf16;

__device__ __forceinline__ float b2f(bf16 x) { return __bfloat162float(x); }
__device__ __forceinline__ bf16 f2b(float x) { return __float2bfloat16(x); }

__device__ __forceinline__ float ldf(const void* p, long long i, int f32) {
    return f32 ? ((const float*)p)[i] : b2f(((const bf16*)p)[i]);
}
__device__ __forceinline__ void stf(void* p, long long i, int f32, float v) {
    if (f32) ((float*)p)[i] = v;
    else     ((bf16*)p)[i] = f2b(v);
}

// ---- paired (2-element) helpers: pair index pi covers elements 2pi, 2pi+1 ----
__device__ __forceinline__ float bfb2f(unsigned short s) {
    return __uint_as_float(((unsigned)s) << 16);
}
__device__ __forceinline__ unsigned short f2bfb(float x) {
    bf16 h = f2b(x); unsigned short r; __builtin_memcpy(&r, &h, 2); return r;
}
__device__ __forceinline__ float2 up2(unsigned u) {
    return make_float2(bfb2f((unsigned short)(u & 0xffff)), bfb2f((unsigned short)(u >> 16)));
}
__device__ __forceinline__ unsigned pk2(float a, float b) {
    return (unsigned)f2bfb(a) | ((unsigned)f2bfb(b) << 16);
}
__device__ __forceinline__ float2 ldf2(const void* p, long long pi, int f32) {
    if (f32) return ((const float2*)p)[pi];
    return up2(((const unsigned*)p)[pi]);
}
__device__ __forceinline__ void stf2(void* p, long long pi, int f32, float a, float b) {
    if (f32) ((float2*)p)[pi] = make_float2(a, b);
    else     ((unsigned*)p)[pi] = pk2(a, b);
}

__device__ __forceinline__ float wave_allreduce_sum(float v) {
    for (int m = 32; m > 0; m >>= 1) v += __shfl_xor(v, m, 64);
    return v;
}

// ================= CSR build =================
// hist + folded dtype sniff (adj_val ~ U(0,1): bf16 reinterpretation stays in [0,1])
__global__ void hist_kernel(const int* __restrict__ rows, int* __restrict__ counts,
                            const void* __restrict__ adjval, int* __restrict__ flag) {
    if (blockIdx.x == 0 && threadIdx.x == 0) {
        int f = 0;
        const bf16* p = (const bf16*)adjval;
        for (int i = 0; i < 64; i++) {
            float x = b2f(p[i]);
            if (!(x >= 0.0f && x <= 1.0f)) f = 1;
        }
        *flag = f;
    }
    int e = blockIdx.x * 256 + threadIdx.x;
    if (e < NNZ) atomicAdd(&counts[rows[e]], 1);
}

__global__ void scan_block(const int* __restrict__ counts, int* __restrict__ incl,
                           int* __restrict__ bsums) {
    __shared__ int s[SCAN_BLK];
    int i = blockIdx.x * SCAN_BLK + threadIdx.x;
    int v = (i < N_NODE) ? counts[i] : 0;
    s[threadIdx.x] = v;
    __syncthreads();
    for (int off = 1; off < SCAN_BLK; off <<= 1) {
        int add = (threadIdx.x >= (unsigned)off) ? s[threadIdx.x - off] : 0;
        __syncthreads();
        s[threadIdx.x] += add;
        __syncthreads();
    }
    if (i < N_NODE) incl[i] = s[threadIdx.x];
    if (threadIdx.x == SCAN_BLK - 1) bsums[blockIdx.x] = s[threadIdx.x];
}

__global__ void scan_top(int* __restrict__ bsums, int nb) {   // nb <= 256
    __shared__ int s[256];
    int t = threadIdx.x;
    int v = (t < nb) ? bsums[t] : 0;
    s[t] = v;
    __syncthreads();
    for (int off = 1; off < 256; off <<= 1) {
        int add = (t >= off) ? s[t - off] : 0;
        __syncthreads();
        s[t] += add;
        __syncthreads();
    }
    if (t < nb) bsums[t] = s[t] - v;   // exclusive
}

// cursor aliases counts (same-thread read-then-write)
__global__ void scan_add(const int* __restrict__ counts, const int* __restrict__ incl,
                         const int* __restrict__ bsums, int* __restrict__ row_ptr,
                         int* __restrict__ cursor) {
    int i = blockIdx.x * SCAN_BLK + threadIdx.x;
    if (i < N_NODE) {
        int ex = incl[i] - counts[i] + bsums[blockIdx.x];
        row_ptr[i] = ex;
        cursor[i] = ex;
    }
    if (i == 0) row_ptr[N_NODE] = NNZ;
}

__global__ void permute_edges(const int* __restrict__ arow, const int* __restrict__ acol,
                              const void* __restrict__ aval, int* __restrict__ cursor,
                              int* __restrict__ colp, float* __restrict__ valp,
                              const int* __restrict__ flagp) {
    const int f32 = *flagp;
    int e = blockIdx.x * 256 + threadIdx.x;
    if (e >= NNZ) return;
    int r = arow[e];
    int pos = atomicAdd(&cursor[r], 1);
    colp[pos] = acol[e];
    valp[pos] = ldf(aval, e, f32);
}

// ================= SpMM gather: wave per row, lane<50 handles a column pair ====
__global__ __launch_bounds__(256) void spmm_gather1(
        const int* __restrict__ rp, const int* __restrict__ colp,
        const float* __restrict__ valp, const void* __restrict__ emb,
        unsigned* __restrict__ h1, const int* __restrict__ flagp) {
    const int f32 = *flagp;
    int lane = threadIdx.x & 63;
    int r = blockIdx.x * 4 + (threadIdx.x >> 6);
    if (r >= N_NODE || lane >= 50) return;
    int k0 = rp[r], k1 = rp[r + 1];
    float a0 = 0.f, a1 = 0.f;
    for (int k = k0; k < k1; k++) {
        int cl = colp[k];
        float v = valp[k];
        float2 e = ldf2(emb, (long long)cl * 50 + lane, f32);
        a0 += v * e.x; a1 += v * e.y;
    }
    h1[(long long)r * 50 + lane] = pk2(a0, a1);
}

__global__ __launch_bounds__(256) void spmm_gather2(
        const int* __restrict__ rp, const int* __restrict__ colp,
        const float* __restrict__ valp, const void* __restrict__ emb,
        const unsigned* __restrict__ h1, void* __restrict__ out,
        const int* __restrict__ flagp) {
    const int f32 = *flagp;
    int lane = threadIdx.x & 63;
    int r = blockIdx.x * 4 + (threadIdx.x >> 6);
    if (r >= N_NODE || lane >= 50) return;
    int k0 = rp[r], k1 = rp[r + 1];
    float a0 = 0.f, a1 = 0.f;
    for (int k = k0; k < k1; k++) {
        int cl = colp[k];
        float v = valp[k];
        float2 e = up2(h1[(long long)cl * 50 + lane]);
        a0 += v * e.x; a1 += v * e.y;
    }
    float2 eb = ldf2(emb, (long long)r * 50 + lane, f32);
    float2 h1r = up2(h1[(long long)r * 50 + lane]);
    stf2(out, (long long)r * 50 + lane, f32,
         (eb.x + h1r.x + a0) * (1.0f / 3.0f), (eb.y + h1r.y + a1) * (1.0f / 3.0f));
}

// ================= downstream =================
__global__ __launch_bounds__(256) void rel_rows(
        const void* __restrict__ out, const int* __restrict__ items,
        const void* __restrict__ slen, float* __restrict__ rel,
        const int* __restrict__ flagp) {
    const int f32 = *flagp;
    int lane = threadIdx.x & 63;
    int b = blockIdx.x * 4 + (threadIdx.x >> 6);
    if (b >= BATCH || lane >= 50) return;
    float s0 = 0.f, s1 = 0.f;
    for (int l = 0; l < SLEN; l++) {
        int it = items[b * SLEN + l];
        if (it > 0) {
            float2 e = ldf2(out, (long long)(it - 1) * 50 + lane, f32);
            s0 += e.x; s1 += e.y;
        }
    }
    float inv = 1.0f / ldf(slen, b, f32);
    ((float2*)rel)[b * 50 + lane] = make_float2(s0 * inv, s1 * inv);
}

// Y[i] = M[i,:] @ X   (4 rows/block, M rows staged in LDS, paired X loads)
__global__ __launch_bounds__(256) void bmm_rows(const void* __restrict__ M,
                                                const float* __restrict__ X,
                                                float* __restrict__ Y,
                                                const int* __restrict__ flagp) {
    __shared__ float ms[4][BATCH];
    const int f32 = *flagp;
    int i0 = blockIdx.x * 4;
    int t = threadIdx.x;
    for (int idx = t; idx < 4 * BATCH; idx += 256) {
        int rr = idx >> 10, j = idx & 1023;
        ms[rr][j] = ldf(M, (long long)(i0 + rr) * BATCH + j, f32);
    }
    __syncthreads();
    int w = t >> 6, lane = t & 63;
    if (lane >= 50) return;
    int i = i0 + w;
    const float2* X2 = (const float2*)X;
    float s0 = 0.f, s1 = 0.f;
    for (int j = 0; j < BATCH; j++) {
        float m = ms[w][j];
        float2 x = X2[j * 50 + lane];
        s0 += m * x.x; s1 += m * x.y;
    }
    ((float2*)Y)[i * 50 + lane] = make_float2(s0, s1);
}

__global__ void selu_norm(const float* __restrict__ rel2, float* __restrict__ sess,
                          float* __restrict__ sessT, float* __restrict__ ns,
                          void* __restrict__ out, const int* __restrict__ flagp) {
    const int f32 = *flagp;
    int b = blockIdx.x, t = threadIdx.x;   // 64 threads
    const float sc = 1.0507009873554804934193349852946f;
    const float al = 1.6732632423543772848170429916717f;
    float x0 = (t < EMB) ? rel2[b * EMB + t] : 0.f;
    float x1 = (t + 64 < EMB) ? rel2[b * EMB + t + 64] : 0.f;
    float c0 = (x0 > 0.f) ? sc * x0 : sc * (al * expm1f(x0));
    float c1 = (x1 > 0.f) ? sc * x1 : sc * (al * expm1f(x1));
    if (t >= EMB) c0 = 0.f;
    if (t + 64 >= EMB) c1 = 0.f;
    float nrm = sqrtf(wave_allreduce_sum(c0 * c0 + c1 * c1));
    float l0 = c0 / nrm, l1 = c1 / nrm;
    float nterm = 0.f;
    if (t < EMB) {
        sess[b * EMB + t] = l0;
        sessT[t * BATCH + b] = l0;
        stf(out, OFF_LC + b * EMB + t, f32, l0);
        nterm += l0 * l0 + 1e-6f;
    }
    if (t + 64 < EMB) {
        sess[b * EMB + t + 64] = l1;
        sessT[(t + 64) * BATCH + b] = l1;
        stf(out, OFF_LC + b * EMB + t + 64, f32, l1);
        nterm += l1 * l1 + 1e-6f;
    }
    float n2sum = wave_allreduce_sum(nterm);
    if (t == 0) ns[b] = sqrtf(n2sum);
}

__global__ void neighbor_kernel(const float* __restrict__ sess, const float* __restrict__ sessT,
                                const float* __restrict__ ns, void* __restrict__ out,
                                const int* __restrict__ flagp) {
    __shared__ float si[EMB];
    __shared__ float red[4];
    __shared__ float wrv[4]; __shared__ int wri[4];
    __shared__ float chv[3]; __shared__ int chi[3];
    __shared__ float stv[3];
    const int f32 = *flagp;
    int i = blockIdx.x, t = threadIdx.x;   // 256 threads
    if (t < EMB) si[t] = sess[i * EMB + t];
    __syncthreads();
    float ni = ns[i];
    float d0 = 0.f, d1 = 0.f, d2 = 0.f, d3 = 0.f;
    for (int k = 0; k < EMB; k++) {
        float sv = si[k];
        const float* row = sessT + k * BATCH;
        d0 += sv * row[t];
        d1 += sv * row[t + 256];
        d2 += sv * row[t + 512];
        d3 += sv * row[t + 768];
    }
    float pv0 = expf(d0 / (ni * ns[t]));
    float pv1 = expf(d1 / (ni * ns[t + 256]));
    float pv2 = expf(d2 / (ni * ns[t + 512]));
    float pv3 = expf(d3 / (ni * ns[t + 768]));
    float local = pv0 + pv1 + pv2 + pv3;
    float w = wave_allreduce_sum(local);
    if ((t & 63) == 0) red[t >> 6] = w;
    __syncthreads();
    float S = red[0] + red[1] + red[2] + red[3];

    int c0 = -1, c1 = -1, c2 = -1;
    float pv[4] = {pv0, pv1, pv2, pv3};
    for (int r = 0; r < 3; r++) {
        float bv = -1e30f; int bi = 0x7fffffff;
        #pragma unroll
        for (int m = 0; m < 4; m++) {
            int j = t + (m << 8);
            if (j == c0 || j == c1 || j == c2) continue;
            float v = pv[m];
            if (v > bv || (v == bv && j < bi)) { bv = v; bi = j; }
        }
        #pragma unroll
        for (int off = 1; off < 64; off <<= 1) {
            float ov = __shfl_xor(bv, off);
            int oi = __shfl_xor(bi, off);
            if (ov > bv || (ov == bv && oi < bi)) { bv = ov; bi = oi; }
        }
        if ((t & 63) == 0) { wrv[t >> 6] = bv; wri[t >> 6] = bi; }
        __syncthreads();
        if (t == 0) {
            float fv = wrv[0]; int fi = wri[0];
            for (int wq = 1; wq < 4; wq++) {
                if (wrv[wq] > fv || (wrv[wq] == fv && wri[wq] < fi)) { fv = wrv[wq]; fi = wri[wq]; }
            }
            chv[r] = fv; chi[r] = fi;
        }
        __syncthreads();
        if (r == 0) c0 = chi[0];
        else if (r == 1) c1 = chi[1];
        else c2 = chi[2];
    }
    if (t == 0) {
        float e0 = expf(chv[0] / S), e1 = expf(chv[1] / S), e2 = expf(chv[2] / S);
        float es = e0 + e1 + e2;
        stv[0] = e0 / es; stv[1] = e1 / es; stv[2] = e2 / es;
    }
    __syncthreads();
    if (t < EMB) {
        float o = stv[0] * sess[chi[0] * EMB + t]
                + stv[1] * sess[chi[1] * EMB + t]
                + stv[2] * sess[chi[2] * EMB + t];
        stf(out, OFF_NB + i * EMB + t, f32, o);
    }
}

// fused projector: Z = (ELU(X@W1^T+b1))@W2^T+b2, plus row norm, optional transpose
__global__ __launch_bounds__(256) void proj2(
        const void* __restrict__ X, int x_dual,
        const void* __restrict__ W1, const void* __restrict__ B1,
        const void* __restrict__ W2, const void* __restrict__ B2,
        float* __restrict__ Z, float* __restrict__ ZT, float* __restrict__ nrm,
        const int* __restrict__ flagp) {
    __shared__ float wT[EMB * EMB];          // 40 KB, reused across phases
    __shared__ float bsh[EMB];
    __shared__ float hid[PROJ_ROWS][EMB];
    __shared__ float xr[2][EMB];
    __shared__ float red2[2][2];
    const int f32 = *flagp;
    int t = threadIdx.x;
    int sub = t >> 7, u = t & 127;           // two half-blocks, one row each
    int r0 = blockIdx.x * PROJ_ROWS;
    // ---- phase A: layer 1 ----
    for (int idx = t; idx < EMB * EMB; idx += 256) {
        int o = idx / EMB, k = idx - o * EMB;
        wT[k * EMB + o] = ldf(W1, idx, f32);
    }
    if (t < EMB) bsh[t] = ldf(B1, t, f32);
    __syncthreads();
    for (int pr = 0; pr < PROJ_ROWS; pr += 2) {
        int row = r0 + pr + sub;
        if (u < EMB)
            xr[sub][u] = x_dual ? ldf(X, (long long)row * EMB + u, f32)
                                : ((const float*)X)[row * EMB + u];
        __syncthreads();
        if (u < EMB) {
            float s = bsh[u];
            for (int k = 0; k < EMB; k++) s += xr[sub][k] * wT[k * EMB + u];
            hid[pr + sub][u] = (s > 0.f) ? s : expm1f(s);
        }
        __syncthreads();
    }
    // ---- phase B: layer 2 + norm ----
    for (int idx = t; idx < EMB * EMB; idx += 256) {
        int o = idx / EMB, k = idx - o * EMB;
        wT[k * EMB + o] = ldf(W2, idx, f32);
    }
    if (t < EMB) bsh[t] = ldf(B2, t, f32);
    __syncthreads();
    for (int pr = 0; pr < PROJ_ROWS; pr += 2) {
        int row = r0 + pr + sub;
        float sq = 0.f;
        if (u < EMB) {
            float o = bsh[u];
            const float* h = hid[pr + sub];
            for (int k = 0; k < EMB; k++) o += h[k] * wT[k * EMB + u];
            Z[(long long)row * EMB + u] = o;
            if (ZT) ZT[(long long)u * BATCH + row] = o;
            sq = o * o;
        }
        sq = wave_allreduce_sum(sq);
        int w = t >> 6;
        if ((t & 63) == 0) red2[sub][w & 1] = sq;
        __syncthreads();
        if (u == 0) nrm[row] = sqrtf(red2[sub][0] + red2[sub][1]);
        __syncthreads();
    }
}

__global__ void loss_kernel(const float* __restrict__ z1p, const float* __restrict__ z2pT,
                            const float* __restrict__ n1, const float* __restrict__ n2,
                            float* __restrict__ acc) {
    __shared__ float zi[EMB];
    __shared__ float red[4];
    __shared__ float sdiag;
    int i = blockIdx.x, t = threadIdx.x;   // 256 threads
    if (t < EMB) zi[t] = z1p[i * EMB + t];
    __syncthreads();
    float ni = n1[i];
    float d0 = 0.f, d1 = 0.f, d2 = 0.f, d3 = 0.f;
    for (int k = 0; k < EMB; k++) {
        float zv = zi[k];
        const float* row = z2pT + k * BATCH;
        d0 += zv * row[t];
        d1 += zv * row[t + 256];
        d2 += zv * row[t + 512];
        d3 += zv * row[t + 768];
    }
    float e0 = expf(d0 / (ni * n2[t]) * 5.0f);
    float e1 = expf(d1 / (ni * n2[t + 256]) * 5.0f);
    float e2 = expf(d2 / (ni * n2[t + 512]) * 5.0f);
    float e3 = expf(d3 / (ni * n2[t + 768]) * 5.0f);
    if (t == (i & 255)) {
        int m = i >> 8;
        sdiag = (m == 0) ? e0 : (m == 1) ? e1 : (m == 2) ? e2 : e3;
    }
    float local = e0 + e1 + e2 + e3;
    float w = wave_allreduce_sum(local);
    if ((t & 63) == 0) red[t >> 6] = w;
    __syncthreads();
    if (t == 0) {
        float S = red[0] + red[1] + red[2] + red[3];
        float l = -logf(sdiag / (S + 1e-8f));
        atomicAdd(acc, l * (1.0f / BATCH));
    }
}

__global__ void write_loss(const float* __restrict__ acc, void* __restrict__ out,
                           const int* __restrict__ flagp) {
    stf(out, OFF_LOSS, *flagp, acc[0]);
}

extern "C" void kernel_launch(void* const* d_in, const int* in_sizes, int n_in,
                              void* d_out, int out_size, void* d_ws, size_t ws_size,
                              hipStream_t stream) {
    const void* emb  = d_in[0];
    const void* aval = d_in[1];
    const void* Amat = d_in[2];
    const void* Dmat = d_in[3];
    const void* z2   = d_in[4];
    const void* Wcf1 = d_in[5];
    const void* bcf1 = d_in[6];
    const void* Wcf2 = d_in[7];
    const void* bcf2 = d_in[8];
    const void* Wkg1 = d_in[9];
    const void* bkg1 = d_in[10];
    const void* Wkg2 = d_in[11];
    const void* bkg2 = d_in[12];
    const void* slen = d_in[13];
    const int* arow  = (const int*)d_in[14];
    const int* acol  = (const int*)d_in[15];
    const int* items = (const int*)d_in[16];

    // ---- workspace layout ----
    int* flag      = (int*)d_ws;
    int* counts    = (int*)((char*)d_ws + 256);        // N_NODE (aliased as cursor)
    int* cursor    = counts;
    int* row_ptr   = counts + N_NODE;                  // N_NODE+1
    int* bsums     = row_ptr + N_NODE + 64;            // 256
    int* colp      = bsums + 256;                      // NNZ (also incl-scan scratch)
    float* valp    = (float*)(colp + NNZ);             // NNZ
    unsigned* h1buf = (unsigned*)(valp + NNZ);         // N_NODE*50 pairs (40 MB)
    float* fsmall  = (float*)(h1buf + (long long)N_NODE * 50);
    float* rel   = fsmall;
    float* t1    = rel  + BE;
    float* rel2  = t1   + BE;
    float* sess  = rel2 + BE;
    float* sessT = sess + BE;
    float* z1p   = sessT + BE;
    float* z2p   = z1p  + BE;
    float* z2pT  = z2p  + BE;
    float* ns    = z2pT + BE;
    float* n1    = ns + BATCH;
    float* n2    = n1 + BATCH;
    float* lacc  = n2 + BATCH;

    const int nscan = (N_NODE + SCAN_BLK - 1) / SCAN_BLK;

    // ---- CSR build ----
    hipMemsetAsync(counts, 0, (size_t)N_NODE * sizeof(int), stream);
    hist_kernel<<<(NNZ + 255) / 256, 256, 0, stream>>>(arow, counts, aval, flag);
    scan_block<<<nscan, SCAN_BLK, 0, stream>>>(counts, colp, bsums);
    scan_top<<<1, 256, 0, stream>>>(bsums, nscan);
    scan_add<<<nscan, SCAN_BLK, 0, stream>>>(counts, colp, bsums, row_ptr, cursor);
    permute_edges<<<(NNZ + 255) / 256, 256, 0, stream>>>(arow, acol, aval, cursor,
                                                         colp, valp, flag);

    // ---- HyperConv via gather (wave per row, paired loads) ----
    spmm_gather1<<<(N_NODE + 3) / 4, 256, 0, stream>>>(row_ptr, colp, valp, emb, h1buf, flag);
    spmm_gather2<<<(N_NODE + 3) / 4, 256, 0, stream>>>(row_ptr, colp, valp, emb, h1buf,
                                                       d_out, flag);

    // ---- RelationGAT ----
    rel_rows<<<(BATCH + 3) / 4, 256, 0, stream>>>(d_out, items, slen, rel, flag);
    bmm_rows<<<BATCH / 4, 256, 0, stream>>>(Amat, rel, t1, flag);
    bmm_rows<<<BATCH / 4, 256, 0, stream>>>(Dmat, t1, rel2, flag);
    selu_norm<<<BATCH, 64, 0, stream>>>(rel2, sess, sessT, ns, d_out, flag);

    // ---- FindNeighbors ----
    neighbor_kernel<<<BATCH, 256, 0, stream>>>(sess, sessT, ns, d_out, flag);

    // ---- Contrast_2view (fused projectors) ----
    proj2<<<BATCH / PROJ_ROWS, 256, 0, stream>>>(sess, 0, Wcf1, bcf1, Wcf2, bcf2,
                                                 z1p, nullptr, n1, flag);
    proj2<<<BATCH / PROJ_ROWS, 256, 0, stream>>>(z2, 1, Wkg1, bkg1, Wkg2, bkg2,
                                                 z2p, z2pT, n2, flag);
    hipMemsetAsync(lacc, 0, sizeof(float), stream);
    loss_kernel<<<BATCH, 256, 0, stream>>>(z1p, z2pT, n1, n2, lacc);
    write_loss<<<1, 1, 0, stream>>>(lacc, d_out, flag);
}